// Round 21
// baseline (146.014 us; speedup 1.0000x reference)
//
#include <hip/hip_runtime.h>
#include <hip/hip_bf16.h>

#define BD 4096
#define ID 1024
#define FD 2048

typedef __bf16 v8bf __attribute__((ext_vector_type(8)));
typedef float  v4f  __attribute__((ext_vector_type(4)));

struct alignas(8) bf4 { __hip_bfloat16 x, y, z, w; };

__device__ inline __hip_bfloat16 bf(float f) { return __float2bfloat16(f); }
__device__ inline float sig(float x) { return 1.f / (1.f + expf(-x)); }
// fast tanh: 1 - 2/(exp(2x)+1); exact at +/-inf, ~1e-6 abs error
__device__ inline float tanh_fast(float x) {
  float e = __expf(2.f * x);
  return 1.f - 2.f * __builtin_amdgcn_rcpf(e + 1.f);
}

__device__ inline void gload16(const __hip_bfloat16* g, __hip_bfloat16* l) {
  __builtin_amdgcn_global_load_lds(
      (const __attribute__((address_space(1))) void*)g,
      (__attribute__((address_space(3))) void*)l, 16, 0, 0);
}

// block-range boundaries inside k_mega
#define MB_CAST  12288   // (BD*ID + BD*FD)/4/256
#define MB_PREP  (MB_CAST + 8)
#define MB_TCW   (MB_PREP + 2048)    // W_in tcast (64,32)
#define MB_TCM   (MB_TCW + 4096)     // M tcast (64,64)
#define MB_MV    (MB_TCM + 256)      // matvec partials 8j x 16p x 2z

// ---------- mega prep kernel: cast | prep_q | tcast W | tcast M | matvec ----
__global__ void k_mega(
    const float* __restrict__ inputs, const float* __restrict__ hidden,
    const float* __restrict__ W_in, const float* __restrict__ primary,
    const float* __restrict__ ent_mat, const float* __restrict__ corr,
    const float* __restrict__ W_tau, const float* __restrict__ W_dec,
    const float* __restrict__ ar, const float* __restrict__ ai,
    const float* __restrict__ ph, const int* __restrict__ tstep,
    __hip_bfloat16* __restrict__ inputs_bf, __hip_bfloat16* __restrict__ hidden_bf,
    __hip_bfloat16* __restrict__ WT, __hip_bfloat16* __restrict__ MT,
    float* __restrict__ qs, float* __restrict__ pamp,
    float* __restrict__ ptau, float* __restrict__ pdec) {
  __shared__ float tbuf[32][33];   // tcast staging
  __shared__ float q[128];         // matvec qs slice
  const int b = blockIdx.x, tid = threadIdx.x;

  if (b < MB_CAST) {               // ---- f32 -> bf16 cast (inputs, hidden)
    int i = b * 256 + tid;
    const float* src = inputs; __hip_bfloat16* dst = inputs_bf;
    int n1 = BD * ID / 4;
    if (i >= n1) { i -= n1; src = hidden; dst = hidden_bf; }
    float4 v = ((const float4*)src)[i];
    bf4 o{bf(v.x), bf(v.y), bf(v.z), bf(v.w)};
    ((bf4*)dst)[i] = o;

  } else if (b < MB_PREP) {        // ---- quantum state prep
    int j = (b - MB_CAST) * 256 + tid;
    float t = (float)tstep[0];
    float4 a = ((const float4*)ar)[j];
    float4 bb = ((const float4*)ai)[j];
    float4 p = ((const float4*)ph)[j];
    float sr = 0.f, si = 0.f, pm = 0.f;
#pragma unroll
    for (int k = 0; k < 4; k++) {
      float pk = (&p.x)[k] + 0.1f * t;
      float rc = (&a.x)[k] * cosf(pk), ic = (&bb.x)[k] * sinf(pk);
      sr += rc; si += ic; pm += rc * rc + ic * ic;
    }
    qs[j] = sr * expf(-si * si);
    pamp[j] = 0.25f * pm;

  } else if (b < MB_TCM) {         // ---- transpose+cast (W_in or M)
    int isM = (b >= MB_TCW);
    int b2 = b - (isM ? MB_TCW : MB_PREP);
    const float* src = isM ? primary : W_in;
    const float* src2 = ent_mat;
    __hip_bfloat16* dst = isM ? MT : WT;
    int C = FD, R = isM ? FD : ID;
    int tx = tid & 31, ty = tid >> 5;
    int x = (b2 & 63) * 32 + tx;          // src col
    int yb = (b2 >> 6) * 32;              // src row base
    float cr = isM ? corr[x] : 0.f;
#pragma unroll
    for (int j = 0; j < 4; j++) {
      int y = yb + ty + j * 8;
      float v = src[(size_t)y * C + x];
      if (isM) v += src2[(size_t)y * C + x] * cr;
      tbuf[ty + j * 8][tx] = v;
    }
    __syncthreads();
#pragma unroll
    for (int j = 0; j < 4; j++) {
      int orow = (b2 & 63) * 32 + ty + j * 8;  // = src col
      int ocol = yb + tx;                      // = src row
      dst[(size_t)orow * R + ocol] = bf(tbuf[tx][ty + j * 8]);
    }

  } else {                         // ---- matvec partials (no atomics)
    int b2 = b - MB_TCM;           // [0,256)
    int jb = b2 & 7, p = (b2 >> 3) & 15, z = b2 >> 7;
    int i0 = p * 128;
    if (tid < 128) {               // recompute qs slice locally
      int i = i0 + tid;
      float t = (float)tstep[0];
      float4 a = ((const float4*)ar)[i];
      float4 bb = ((const float4*)ai)[i];
      float4 pp = ((const float4*)ph)[i];
      float sr = 0.f, si = 0.f;
#pragma unroll
      for (int k = 0; k < 4; k++) {
        float pk = (&pp.x)[k] + 0.1f * t;
        sr += (&a.x)[k] * cosf(pk);
        si += (&bb.x)[k] * sinf(pk);
      }
      q[tid] = sr * expf(-si * si);
    }
    __syncthreads();
    const float* W = z ? W_dec : W_tau;
    float* outp = z ? pdec : ptau;
    int j = jb * 256 + tid;
    float acc = 0.f;
#pragma unroll 8
    for (int i = 0; i < 128; i++)
      acc = fmaf(q[i], W[(size_t)(i0 + i) * FD + j], acc);
    outp[p * FD + j] = acc;        // plain store
  }
}

// ---------- balanced GEMM (all blocks 48 K-steps) + post in z=2 plane ------
// grid (32,16,3):
//  z=0: ent K=[0,1536)  (48 steps) -> ge
//  z=1: ent K=[1536,2048) (16 steps) -> g2; zero acc; xproj (32 steps) -> gx
//  z=2: blocks (0, y<8) run k_post's work (inputs all from k_mega); rest exit.
// 1024 compute blocks = exactly 4/CU throughout (no 2/CU tail phase).
__global__ __launch_bounds__(256, 4) void k_gemm3(
    const __hip_bfloat16* __restrict__ Ah,   // hidden bf16 [BD][FD]
    const __hip_bfloat16* __restrict__ MT,   // [FD][FD]  (B stored [N][K])
    const __hip_bfloat16* __restrict__ Ax,   // inputs bf16 [BD][ID]
    const __hip_bfloat16* __restrict__ WT,   // [FD][ID]
    const float* __restrict__ ptau, const float* __restrict__ pdec,
    const float* __restrict__ qs, const float* __restrict__ b_tau,
    const float* __restrict__ b_dec, const int* __restrict__ tstep,
    float* __restrict__ s_arr, float* __restrict__ qact,
    float* __restrict__ tpart, float* __restrict__ dpart,
    __hip_bfloat16* __restrict__ ge, __hip_bfloat16* __restrict__ g2,
    __hip_bfloat16* __restrict__ gx) {
  __shared__ alignas(16) __hip_bfloat16 As[2][128][32];   // 16 KB
  __shared__ alignas(16) __hip_bfloat16 Bs[2][128][32];   // 16 KB
  __shared__ float rt[4], rd[4];

  const int tid = threadIdx.x;

  if (blockIdx.z == 2) {           // ---- post work (former k_post), 8 blocks
    if (blockIdx.x != 0 || blockIdx.y >= 8) return;
    int j = blockIdx.y * 256 + tid;
    float tr = b_tau[j], dr = b_dec[j];
#pragma unroll
    for (int p = 0; p < 16; p++) {
      tr += ptau[p * FD + j];
      dr += pdec[p * FD + j];
    }
    float t = (float)tstep[0];
    float coh = expf(-0.01f * t);
    float tq = (5.f + 45.f * sig(tr)) / 3.2f;
    s_arr[j] = 0.03125f / tq;
    float dec = sig(dr);
    qact[j] = qs[j] * dec * coh;
    float tsum = tq, dsum = dec;
    for (int off = 32; off; off >>= 1) {
      tsum += __shfl_down(tsum, off);
      dsum += __shfl_down(dsum, off);
    }
    int w = tid >> 6;
    if ((tid & 63) == 0) { rt[w] = tsum; rd[w] = dsum; }
    __syncthreads();
    if (tid == 0) {
      tpart[blockIdx.y] = rt[0] + rt[1] + rt[2] + rt[3];
      dpart[blockIdx.y] = rd[0] + rd[1] + rd[2] + rd[3];
    }
    return;
  }

  const int l = tid & 63, w = tid >> 6;
  const int wr = w >> 1, wc = w & 1;     // wave tile: 64 rows x 64 cols
  const int row0 = blockIdx.x * 128, col0 = blockIdx.y * 128;

  v4f acc[4][4];
#pragma unroll
  for (int i = 0; i < 4; i++)
#pragma unroll
    for (int j = 0; j < 4; j++) acc[i][j] = (v4f)0.f;

  const int srow = l >> 2;
  const int scol = ((l & 3) ^ ((l >> 3) & 3)) * 8;
  const int rcol = ((l >> 4) ^ ((l >> 1) & 3)) * 8;

  auto stage = [&](int buf, const __hip_bfloat16* A, const __hip_bfloat16* B,
                   int ld, int k) {
#pragma unroll
    for (int i = 0; i < 2; i++) {
      int rr = w * 32 + i * 16;
      gload16(A + (size_t)(row0 + rr + srow) * ld + k + scol, &As[buf][rr][0]);
      gload16(B + (size_t)(col0 + rr + srow) * ld + k + scol, &Bs[buf][rr][0]);
    }
  };
  auto compute = [&](int buf) {
    v8bf a[4], b[4];
#pragma unroll
    for (int mi = 0; mi < 4; mi++)
      a[mi] = *(const v8bf*)&As[buf][wr * 64 + mi * 16 + (l & 15)][rcol];
#pragma unroll
    for (int ni = 0; ni < 4; ni++)
      b[ni] = *(const v8bf*)&Bs[buf][wc * 64 + ni * 16 + (l & 15)][rcol];
#pragma unroll
    for (int mi = 0; mi < 4; mi++)
#pragma unroll
      for (int ni = 0; ni < 4; ni++)
        acc[mi][ni] = __builtin_amdgcn_mfma_f32_16x16x32_bf16(a[mi], b[ni], acc[mi][ni], 0, 0, 0);
  };
  auto run = [&](const __hip_bfloat16* A, const __hip_bfloat16* B, int ld,
                 int kb, int nkt) {
    stage(0, A, B, ld, kb);
    __syncthreads();
    for (int kt = 0; kt < nkt; kt++) {
      if (kt + 1 < nkt) stage((kt + 1) & 1, A, B, ld, kb + (kt + 1) * 32);
      compute(kt & 1);
      __syncthreads();
    }
  };
  auto writeout = [&](__hip_bfloat16* gout) {
#pragma unroll
    for (int ni = 0; ni < 4; ni++) {
      int gc = col0 + wc * 64 + ni * 16 + (l & 15);
#pragma unroll
      for (int mi = 0; mi < 4; mi++) {
        int gr0 = row0 + wr * 64 + mi * 16 + (l >> 4) * 4;
#pragma unroll
        for (int e = 0; e < 4; e++)
          gout[(size_t)(gr0 + e) * FD + gc] = bf(acc[mi][ni][e]);
      }
    }
  };

  if (blockIdx.z == 0) {
    run(Ah, MT, FD, 0, 48);            // ent K=[0,1536)
    writeout(ge);
  } else {
    run(Ah, MT, FD, 1536, 16);         // ent K=[1536,2048)
    writeout(g2);
#pragma unroll
    for (int i = 0; i < 4; i++)
#pragma unroll
      for (int j = 0; j < 4; j++) acc[i][j] = (v4f)0.f;
    run(Ax, WT, ID, 0, 32);            // xproj K=[0,1024)
    writeout(gx);
  }
}

// ---------- combine: streaming h-update + d_amp + |ent| row partial --------
__global__ __launch_bounds__(256) void k_comb(
    const __hip_bfloat16* __restrict__ ge, const __hip_bfloat16* __restrict__ g2,
    const __hip_bfloat16* __restrict__ gx, const __hip_bfloat16* __restrict__ hbf,
    const float* __restrict__ b_in, const float* __restrict__ s_arr,
    const float* __restrict__ qact, const float* __restrict__ pamp,
    float* __restrict__ entpart, float* __restrict__ out) {
  const int row = blockIdx.x;
  const size_t rb = (size_t)row * FD;
  float asum = 0.f;
#pragma unroll
  for (int half = 0; half < 2; half++) {
    const int c = half * 1024 + threadIdx.x * 4;
    const size_t base = rb + c;
    bf4 e0 = *(const bf4*)(ge + base);
    bf4 e1 = *(const bf4*)(g2 + base);
    bf4 xx = *(const bf4*)(gx + base);
    bf4 hh = *(const bf4*)(hbf + base);
    float4 bi = *(const float4*)&b_in[c];
    float4 sj = *(const float4*)&s_arr[c];
    float4 qa = *(const float4*)&qact[c];
    float4 pm = *(const float4*)&pamp[c];
    float o[4];
#pragma unroll
    for (int j = 0; j < 4; j++) {
      float e = __bfloat162float((&e0.x)[j]) + __bfloat162float((&e1.x)[j]);
      asum += fabsf(e);
      float g = e + __bfloat162float((&xx.x)[j]) + (&bi.x)[j];
      float comb = tanh_fast(g) + (&qa.x)[j];
      float h = __bfloat162float((&hh.x)[j]);
      o[j] = fmaf((&sj.x)[j], comb - h, h);
    }
    *(float4*)&out[base] = make_float4(o[0], o[1], o[2], o[3]);
    *(float4*)&out[(size_t)BD * FD + base] = pm;
  }

  for (int off = 32; off; off >>= 1) asum += __shfl_down(asum, off);
  __shared__ float red[4];
  if ((threadIdx.x & 63) == 0) red[threadIdx.x >> 6] = asum;
  __syncthreads();
  if (threadIdx.x == 0)
    entpart[row] = red[0] + red[1] + red[2] + red[3];
}

// ---------- finalize: reduce entpart(4096) + tpart + dpart ----------
__global__ void k_fin(const float* __restrict__ entpart, const float* __restrict__ tpart,
                      const float* __restrict__ dpart, const int* tstep, float* out3) {
  float s = 0.f;
  for (int i = threadIdx.x; i < BD; i += 256) s += entpart[i];
  for (int off = 32; off; off >>= 1) s += __shfl_down(s, off);
  __shared__ float red[4];
  if ((threadIdx.x & 63) == 0) red[threadIdx.x >> 6] = s;
  __syncthreads();
  if (threadIdx.x == 0) {
    float tot = red[0] + red[1] + red[2] + red[3];
    float ts = 0.f, ds = 0.f;
#pragma unroll
    for (int i = 0; i < 8; i++) { ts += tpart[i]; ds += dpart[i]; }
    float t = (float)tstep[0];
    out3[0] = expf(-0.01f * t);
    out3[1] = tot / (float)((size_t)BD * FD);
    out3[2] = ds / (float)FD;
    out3[3] = ts / (float)FD;
  }
}

extern "C" void kernel_launch(void* const* d_in, const int* in_sizes, int n_in,
                              void* d_out, int out_size, void* d_ws, size_t ws_size,
                              hipStream_t stream) {
  const float* inputs  = (const float*)d_in[0];
  const float* hidden  = (const float*)d_in[1];
  const float* W_in    = (const float*)d_in[2];
  const float* b_in    = (const float*)d_in[3];
  const float* amp_r   = (const float*)d_in[4];
  const float* amp_i   = (const float*)d_in[5];
  const float* phase   = (const float*)d_in[6];
  const float* primary = (const float*)d_in[7];
  const float* ent_mat = (const float*)d_in[8];
  const float* corr    = (const float*)d_in[9];
  const float* W_tau   = (const float*)d_in[10];
  const float* b_tau   = (const float*)d_in[11];
  const float* W_dec   = (const float*)d_in[12];
  const float* b_dec   = (const float*)d_in[13];
  const int*   tstep   = (const int*)d_in[14];

  char* ws = (char*)d_ws;
  __hip_bfloat16* inputs_bf = (__hip_bfloat16*)(ws + 0);         //  8 MB
  __hip_bfloat16* hidden_bf = (__hip_bfloat16*)(ws + 8388608);   // 16 MB
  __hip_bfloat16* WT        = (__hip_bfloat16*)(ws + 25165824);  //  4 MB
  __hip_bfloat16* MT        = (__hip_bfloat16*)(ws + 29360128);  //  8 MB
  __hip_bfloat16* ge        = (__hip_bfloat16*)(ws + 37748736);  // 16 MB
  __hip_bfloat16* gx        = (__hip_bfloat16*)(ws + 54525952);  // 16 MB
  __hip_bfloat16* g2        = (__hip_bfloat16*)(ws + 71303168);  // 16 MB

  char* sb = ws + 88080384;
  float* qs      = (float*)(sb);
  float* pamp    = (float*)(sb + 8192);
  float* s_arr   = (float*)(sb + 2 * 8192);
  float* qact    = (float*)(sb + 3 * 8192);
  float* ptau    = (float*)(sb + 4 * 8192);             // 16x2048 = 128 KB
  float* pdec    = (float*)(sb + 4 * 8192 + 131072);    // 128 KB
  float* entpart = (float*)(sb + 4 * 8192 + 262144);    // 4096 f32 = 16 KB
  float* tpart   = (float*)(sb + 4 * 8192 + 262144 + 16384);
  float* dpart   = (float*)(sb + 4 * 8192 + 262144 + 16384 + 64);

  float* out = (float*)d_out;

  hipLaunchKernelGGL(k_mega, dim3(MB_MV), dim3(256), 0, stream,
                     inputs, hidden, W_in, primary, ent_mat, corr, W_tau, W_dec,
                     amp_r, amp_i, phase, tstep,
                     inputs_bf, hidden_bf, WT, MT, qs, pamp, ptau, pdec);
  hipLaunchKernelGGL(k_gemm3, dim3(32, 16, 3), dim3(256), 0, stream,
                     hidden_bf, MT, inputs_bf, WT,
                     ptau, pdec, qs, b_tau, b_dec, tstep,
                     s_arr, qact, tpart, dpart, ge, g2, gx);
  hipLaunchKernelGGL(k_comb, dim3(BD), dim3(256), 0, stream,
                     ge, g2, gx, hidden_bf, b_in, s_arr, qact, pamp,
                     entpart, out);
  hipLaunchKernelGGL(k_fin, dim3(1), dim3(256), 0, stream,
                     entpart, tpart, dpart, tstep, out + (size_t)2 * BD * FD);
}

// Round 22
// 117.953 us; speedup vs baseline: 1.2379x; 1.2379x over previous
//
#include <hip/hip_runtime.h>
#include <hip/hip_bf16.h>

#define BD 4096
#define ID 1024
#define FD 2048

typedef __bf16 v8bf __attribute__((ext_vector_type(8)));
typedef float  v4f  __attribute__((ext_vector_type(4)));

struct alignas(8) bf4 { __hip_bfloat16 x, y, z, w; };

__device__ inline __hip_bfloat16 bf(float f) { return __float2bfloat16(f); }
__device__ inline float sig(float x) { return 1.f / (1.f + expf(-x)); }
// fast tanh: 1 - 2/(exp(2x)+1); exact at +/-inf, ~1e-6 abs error
__device__ inline float tanh_fast(float x) {
  float e = __expf(2.f * x);
  return 1.f - 2.f * __builtin_amdgcn_rcpf(e + 1.f);
}

__device__ inline void gload16(const __hip_bfloat16* g, __hip_bfloat16* l) {
  __builtin_amdgcn_global_load_lds(
      (const __attribute__((address_space(1))) void*)g,
      (__attribute__((address_space(3))) void*)l, 16, 0, 0);
}

// block-range boundaries inside k_mega
#define MB_CAST  12288   // (BD*ID + BD*FD)/4/256
#define MB_PREP  (MB_CAST + 8)
#define MB_TCW   (MB_PREP + 2048)    // W_in tcast (64,32)
#define MB_TCM   (MB_TCW + 4096)     // M tcast (64,64)
#define MB_MV    (MB_TCM + 256)      // matvec partials 8j x 16p x 2z

// ---------- mega prep kernel: cast | prep_q | tcast W | tcast M | matvec ----
__global__ void k_mega(
    const float* __restrict__ inputs, const float* __restrict__ hidden,
    const float* __restrict__ W_in, const float* __restrict__ primary,
    const float* __restrict__ ent_mat, const float* __restrict__ corr,
    const float* __restrict__ W_tau, const float* __restrict__ W_dec,
    const float* __restrict__ ar, const float* __restrict__ ai,
    const float* __restrict__ ph, const int* __restrict__ tstep,
    __hip_bfloat16* __restrict__ inputs_bf, __hip_bfloat16* __restrict__ hidden_bf,
    __hip_bfloat16* __restrict__ WT, __hip_bfloat16* __restrict__ MT,
    float* __restrict__ qs, float* __restrict__ pamp,
    float* __restrict__ ptau, float* __restrict__ pdec) {
  __shared__ float tbuf[32][33];   // tcast staging
  __shared__ float q[128];         // matvec qs slice
  const int b = blockIdx.x, tid = threadIdx.x;

  if (b < MB_CAST) {               // ---- f32 -> bf16 cast (inputs, hidden)
    int i = b * 256 + tid;
    const float* src = inputs; __hip_bfloat16* dst = inputs_bf;
    int n1 = BD * ID / 4;
    if (i >= n1) { i -= n1; src = hidden; dst = hidden_bf; }
    float4 v = ((const float4*)src)[i];
    bf4 o{bf(v.x), bf(v.y), bf(v.z), bf(v.w)};
    ((bf4*)dst)[i] = o;

  } else if (b < MB_PREP) {        // ---- quantum state prep
    int j = (b - MB_CAST) * 256 + tid;
    float t = (float)tstep[0];
    float4 a = ((const float4*)ar)[j];
    float4 bb = ((const float4*)ai)[j];
    float4 p = ((const float4*)ph)[j];
    float sr = 0.f, si = 0.f, pm = 0.f;
#pragma unroll
    for (int k = 0; k < 4; k++) {
      float pk = (&p.x)[k] + 0.1f * t;
      float rc = (&a.x)[k] * cosf(pk), ic = (&bb.x)[k] * sinf(pk);
      sr += rc; si += ic; pm += rc * rc + ic * ic;
    }
    qs[j] = sr * expf(-si * si);
    pamp[j] = 0.25f * pm;

  } else if (b < MB_TCM) {         // ---- transpose+cast (W_in or M)
    int isM = (b >= MB_TCW);
    int b2 = b - (isM ? MB_TCW : MB_PREP);
    const float* src = isM ? primary : W_in;
    const float* src2 = ent_mat;
    __hip_bfloat16* dst = isM ? MT : WT;
    int C = FD, R = isM ? FD : ID;
    int tx = tid & 31, ty = tid >> 5;
    int x = (b2 & 63) * 32 + tx;          // src col
    int yb = (b2 >> 6) * 32;              // src row base
    float cr = isM ? corr[x] : 0.f;
#pragma unroll
    for (int j = 0; j < 4; j++) {
      int y = yb + ty + j * 8;
      float v = src[(size_t)y * C + x];
      if (isM) v += src2[(size_t)y * C + x] * cr;
      tbuf[ty + j * 8][tx] = v;
    }
    __syncthreads();
#pragma unroll
    for (int j = 0; j < 4; j++) {
      int orow = (b2 & 63) * 32 + ty + j * 8;  // = src col
      int ocol = yb + tx;                      // = src row
      dst[(size_t)orow * R + ocol] = bf(tbuf[tx][ty + j * 8]);
    }

  } else {                         // ---- matvec partials (no atomics)
    int b2 = b - MB_TCM;           // [0,256)
    int jb = b2 & 7, p = (b2 >> 3) & 15, z = b2 >> 7;
    int i0 = p * 128;
    if (tid < 128) {               // recompute qs slice locally
      int i = i0 + tid;
      float t = (float)tstep[0];
      float4 a = ((const float4*)ar)[i];
      float4 bb = ((const float4*)ai)[i];
      float4 pp = ((const float4*)ph)[i];
      float sr = 0.f, si = 0.f;
#pragma unroll
      for (int k = 0; k < 4; k++) {
        float pk = (&pp.x)[k] + 0.1f * t;
        sr += (&a.x)[k] * cosf(pk);
        si += (&bb.x)[k] * sinf(pk);
      }
      q[tid] = sr * expf(-si * si);
    }
    __syncthreads();
    const float* W = z ? W_dec : W_tau;
    float* outp = z ? pdec : ptau;
    int j = jb * 256 + tid;
    float acc = 0.f;
#pragma unroll 8
    for (int i = 0; i < 128; i++)
      acc = fmaf(q[i], W[(size_t)(i0 + i) * FD + j], acc);
    outp[p * FD + j] = acc;        // plain store
  }
}

// ---------- post: reduce partials, tau_q/s/deco/qact, block sums ----------
__global__ void k_post(const float* __restrict__ ptau, const float* __restrict__ pdec,
                       const float* __restrict__ qs, const float* __restrict__ b_tau,
                       const float* __restrict__ b_dec, const int* tstep,
                       float* __restrict__ s_arr, float* __restrict__ qact,
                       float* __restrict__ tpart, float* __restrict__ dpart) {
  int j = blockIdx.x * 256 + threadIdx.x;
  float tr = b_tau[j], dr = b_dec[j];
#pragma unroll
  for (int p = 0; p < 16; p++) {
    tr += ptau[p * FD + j];
    dr += pdec[p * FD + j];
  }
  float t = (float)tstep[0];
  float coh = expf(-0.01f * t);
  float tq = (5.f + 45.f * sig(tr)) / 3.2f;
  s_arr[j] = 0.03125f / tq;
  float dec = sig(dr);
  qact[j] = qs[j] * dec * coh;
  float tsum = tq, dsum = dec;
  for (int off = 32; off; off >>= 1) {
    tsum += __shfl_down(tsum, off);
    dsum += __shfl_down(dsum, off);
  }
  __shared__ float rt[4], rd[4];
  int w = threadIdx.x >> 6;
  if ((threadIdx.x & 63) == 0) { rt[w] = tsum; rd[w] = dsum; }
  __syncthreads();
  if (threadIdx.x == 0) {
    tpart[blockIdx.x] = rt[0] + rt[1] + rt[2] + rt[3];
    dpart[blockIdx.x] = rd[0] + rd[1] + rd[2] + rd[3];
  }
}

// ---------- GEMM 2-part: z=0 ent full K=2048 -> ge (+ |ent| partials);
// z=1 xproj -> gx. 128x128 tile, 2-barrier dbuf + XOR swizzle, 1024 blocks.
__global__ __launch_bounds__(256, 4) void k_gemm2(
    const __hip_bfloat16* __restrict__ Ah,   // hidden bf16 [BD][FD]
    const __hip_bfloat16* __restrict__ MT,   // [FD][FD]  (B stored [N][K])
    const __hip_bfloat16* __restrict__ Ax,   // inputs bf16 [BD][ID]
    const __hip_bfloat16* __restrict__ WT,   // [FD][ID]
    __hip_bfloat16* __restrict__ ge, __hip_bfloat16* __restrict__ gx,
    float* __restrict__ entpart) {
  __shared__ alignas(16) __hip_bfloat16 As[2][128][32];   // 16 KB
  __shared__ alignas(16) __hip_bfloat16 Bs[2][128][32];   // 16 KB

  const int tid = threadIdx.x;
  const int l = tid & 63, w = tid >> 6;
  const int wr = w >> 1, wc = w & 1;     // wave tile: 64 rows x 64 cols
  const int row0 = blockIdx.x * 128, col0 = blockIdx.y * 128;
  const int bz = blockIdx.z;

  const __hip_bfloat16* A = bz ? Ax : Ah;
  const __hip_bfloat16* B = bz ? WT : MT;
  const int ld = bz ? ID : FD;
  const int nkt = bz ? 32 : 64;
  __hip_bfloat16* gout = bz ? gx : ge;

  v4f acc[4][4];
#pragma unroll
  for (int i = 0; i < 4; i++)
#pragma unroll
    for (int j = 0; j < 4; j++) acc[i][j] = (v4f)0.f;

  const int srow = l >> 2;
  const int scol = ((l & 3) ^ ((l >> 3) & 3)) * 8;
  const int rcol = ((l >> 4) ^ ((l >> 1) & 3)) * 8;

  auto stage = [&](int buf, int kt) {
    int k = kt * 32;
#pragma unroll
    for (int i = 0; i < 2; i++) {
      int rr = w * 32 + i * 16;
      gload16(A + (size_t)(row0 + rr + srow) * ld + k + scol, &As[buf][rr][0]);
      gload16(B + (size_t)(col0 + rr + srow) * ld + k + scol, &Bs[buf][rr][0]);
    }
  };
  auto compute = [&](int buf) {
    v8bf a[4], b[4];
#pragma unroll
    for (int mi = 0; mi < 4; mi++)
      a[mi] = *(const v8bf*)&As[buf][wr * 64 + mi * 16 + (l & 15)][rcol];
#pragma unroll
    for (int ni = 0; ni < 4; ni++)
      b[ni] = *(const v8bf*)&Bs[buf][wc * 64 + ni * 16 + (l & 15)][rcol];
#pragma unroll
    for (int mi = 0; mi < 4; mi++)
#pragma unroll
      for (int ni = 0; ni < 4; ni++)
        acc[mi][ni] = __builtin_amdgcn_mfma_f32_16x16x32_bf16(a[mi], b[ni], acc[mi][ni], 0, 0, 0);
  };

  stage(0, 0);
  __syncthreads();
  for (int kt = 0; kt < nkt; kt++) {
    if (kt + 1 < nkt) stage((kt + 1) & 1, kt + 1);
    compute(kt & 1);
    __syncthreads();
  }

  float asum = 0.f;
#pragma unroll
  for (int ni = 0; ni < 4; ni++) {
    int gc = col0 + wc * 64 + ni * 16 + (l & 15);
#pragma unroll
    for (int mi = 0; mi < 4; mi++) {
      int gr0 = row0 + wr * 64 + mi * 16 + (l >> 4) * 4;
#pragma unroll
      for (int e = 0; e < 4; e++) {
        float v = acc[mi][ni][e];
        asum += fabsf(v);
        gout[(size_t)(gr0 + e) * FD + gc] = bf(v);
      }
    }
  }
  if (bz == 0) {   // |ent| per-wave partial (f32-accurate, free here)
    for (int off = 32; off; off >>= 1) asum += __shfl_down(asum, off);
    if (l == 0) entpart[(blockIdx.x * 16 + blockIdx.y) * 4 + w] = asum;
  }
}

// ---------- combine: streaming h-update + d_amp; block BD = scalar finalize -
__global__ __launch_bounds__(256) void k_comb(
    const __hip_bfloat16* __restrict__ ge, const __hip_bfloat16* __restrict__ gx,
    const __hip_bfloat16* __restrict__ hbf,
    const float* __restrict__ b_in, const float* __restrict__ s_arr,
    const float* __restrict__ qact, const float* __restrict__ pamp,
    const float* __restrict__ entpart, const float* __restrict__ tpart,
    const float* __restrict__ dpart, const int* __restrict__ tstep,
    float* __restrict__ out) {
  const int row = blockIdx.x;

  if (row == BD) {   // ---- scalar finalize: one extra block
    float s = 0.f;
    for (int i = threadIdx.x; i < 2048; i += 256) s += entpart[i];
    for (int off = 32; off; off >>= 1) s += __shfl_down(s, off);
    __shared__ float red[4];
    if ((threadIdx.x & 63) == 0) red[threadIdx.x >> 6] = s;
    __syncthreads();
    if (threadIdx.x == 0) {
      float tot = red[0] + red[1] + red[2] + red[3];
      float ts = 0.f, ds = 0.f;
#pragma unroll
      for (int i = 0; i < 8; i++) { ts += tpart[i]; ds += dpart[i]; }
      float t = (float)tstep[0];
      float* o3 = out + (size_t)2 * BD * FD;
      o3[0] = expf(-0.01f * t);
      o3[1] = tot / (float)((size_t)BD * FD);
      o3[2] = ds / (float)FD;
      o3[3] = ts / (float)FD;
    }
    return;
  }

  const size_t rb = (size_t)row * FD;
#pragma unroll
  for (int half = 0; half < 2; half++) {
    const int c = half * 1024 + threadIdx.x * 4;
    const size_t base = rb + c;
    bf4 e0 = *(const bf4*)(ge + base);
    bf4 xx = *(const bf4*)(gx + base);
    bf4 hh = *(const bf4*)(hbf + base);
    float4 bi = *(const float4*)&b_in[c];
    float4 sj = *(const float4*)&s_arr[c];
    float4 qa = *(const float4*)&qact[c];
    float4 pm = *(const float4*)&pamp[c];
    float o[4];
#pragma unroll
    for (int j = 0; j < 4; j++) {
      float g = __bfloat162float((&e0.x)[j]) + __bfloat162float((&xx.x)[j]) + (&bi.x)[j];
      float comb = tanh_fast(g) + (&qa.x)[j];
      float h = __bfloat162float((&hh.x)[j]);
      o[j] = fmaf((&sj.x)[j], comb - h, h);
    }
    *(float4*)&out[base] = make_float4(o[0], o[1], o[2], o[3]);
    *(float4*)&out[(size_t)BD * FD + base] = pm;
  }
}

extern "C" void kernel_launch(void* const* d_in, const int* in_sizes, int n_in,
                              void* d_out, int out_size, void* d_ws, size_t ws_size,
                              hipStream_t stream) {
  const float* inputs  = (const float*)d_in[0];
  const float* hidden  = (const float*)d_in[1];
  const float* W_in    = (const float*)d_in[2];
  const float* b_in    = (const float*)d_in[3];
  const float* amp_r   = (const float*)d_in[4];
  const float* amp_i   = (const float*)d_in[5];
  const float* phase   = (const float*)d_in[6];
  const float* primary = (const float*)d_in[7];
  const float* ent_mat = (const float*)d_in[8];
  const float* corr    = (const float*)d_in[9];
  const float* W_tau   = (const float*)d_in[10];
  const float* b_tau   = (const float*)d_in[11];
  const float* W_dec   = (const float*)d_in[12];
  const float* b_dec   = (const float*)d_in[13];
  const int*   tstep   = (const int*)d_in[14];

  char* ws = (char*)d_ws;
  __hip_bfloat16* inputs_bf = (__hip_bfloat16*)(ws + 0);         //  8 MB
  __hip_bfloat16* hidden_bf = (__hip_bfloat16*)(ws + 8388608);   // 16 MB
  __hip_bfloat16* WT        = (__hip_bfloat16*)(ws + 25165824);  //  4 MB
  __hip_bfloat16* MT        = (__hip_bfloat16*)(ws + 29360128);  //  8 MB
  __hip_bfloat16* ge        = (__hip_bfloat16*)(ws + 37748736);  // 16 MB
  __hip_bfloat16* gx        = (__hip_bfloat16*)(ws + 54525952);  // 16 MB

  char* sb = ws + 71303168;
  float* qs      = (float*)(sb);
  float* pamp    = (float*)(sb + 8192);
  float* s_arr   = (float*)(sb + 2 * 8192);
  float* qact    = (float*)(sb + 3 * 8192);
  float* ptau    = (float*)(sb + 4 * 8192);             // 16x2048 = 128 KB
  float* pdec    = (float*)(sb + 4 * 8192 + 131072);    // 128 KB
  float* entpart = (float*)(sb + 4 * 8192 + 262144);    // 2048 f32 = 8 KB
  float* tpart   = (float*)(sb + 4 * 8192 + 262144 + 8192);
  float* dpart   = (float*)(sb + 4 * 8192 + 262144 + 8192 + 64);

  float* out = (float*)d_out;

  hipLaunchKernelGGL(k_mega, dim3(MB_MV), dim3(256), 0, stream,
                     inputs, hidden, W_in, primary, ent_mat, corr, W_tau, W_dec,
                     amp_r, amp_i, phase, tstep,
                     inputs_bf, hidden_bf, WT, MT, qs, pamp, ptau, pdec);
  hipLaunchKernelGGL(k_post, dim3(8), dim3(256), 0, stream,
                     ptau, pdec, qs, b_tau, b_dec, tstep, s_arr, qact, tpart, dpart);
  hipLaunchKernelGGL(k_gemm2, dim3(32, 16, 2), dim3(256), 0, stream,
                     hidden_bf, MT, inputs_bf, WT, ge, gx, entpart);
  hipLaunchKernelGGL(k_comb, dim3(BD + 1), dim3(256), 0, stream,
                     ge, gx, hidden_bf, b_in, s_arr, qact, pamp,
                     entpart, tpart, dpart, tstep, out);
}